// Round 9
// baseline (176.926 us; speedup 1.0000x reference)
//
#include <hip/hip_runtime.h>

typedef unsigned short u16;
typedef unsigned int u32;

typedef __attribute__((ext_vector_type(4))) float f32x4;
typedef __attribute__((ext_vector_type(8))) short s16x8;
typedef __attribute__((ext_vector_type(4))) u32 u32x4;

__device__ __forceinline__ u16 f2bf(float f) {
    u32 u = __builtin_bit_cast(u32, f);
    u += 0x7fffu + ((u >> 16) & 1u);
    return (u16)(u >> 16);
}

__device__ __forceinline__ u32 pk_bf16(float a, float b) {
    return (u32)f2bf(a) | ((u32)f2bf(b) << 16);
}

// HW packed f32x2 -> bf16x2 (RNE), 1 instr
__device__ __forceinline__ u32 cvtpk(float a, float b) {
    u32 r;
    asm("v_cvt_pk_bf16_f32 %0, %1, %2" : "=v"(r) : "v"(a), "v"(b));
    return r;
}

// gfx950 cross-lane swaps (VALU pipe, both operands updated)
__device__ __forceinline__ void pl32swap(u32& a, u32& b) {
    asm volatile("v_permlane32_swap_b32 %0, %1" : "+v"(a), "+v"(b));
}
__device__ __forceinline__ void pl16swap(u32& a, u32& b) {
    asm volatile("v_permlane16_swap_b32 %0, %1" : "+v"(a), "+v"(b));
}

#define EXP2(x) exp2f(x)

// async global -> LDS, 16B per lane; LDS dest = wave-uniform base + lane*16
__device__ __forceinline__ void gload16(const u16* g, u16* l) {
    __builtin_amdgcn_global_load_lds(
        (const __attribute__((address_space(1))) void*)(const void*)g,
        (__attribute__((address_space(3))) void*)(void*)l, 16, 0, 0);
}

// ---- fused prep: cast x (blocks 0..4095), transpose w_attn (next 3072),
// ---- transpose w_proj (last 1024).  256 threads each.
__global__ void k_prep(const float* __restrict__ x, u16* __restrict__ x_bf,
                       const float* __restrict__ wa, u16* __restrict__ wat,
                       const float* __restrict__ wp, u16* __restrict__ wpt) {
    const int bid = blockIdx.x;
    const int tid = threadIdx.x;
    if (bid < 4096) {  // cast: 4 elems/thread
        int i = (bid * 256 + tid) * 4;
        float4 v = *(const float4*)(x + i);
        uint2 pk;
        pk.x = pk_bf16(v.x, v.y);
        pk.y = pk_bf16(v.z, v.w);
        *(uint2*)(x_bf + i) = pk;
        return;
    }
    // transpose+cast: in [K][N] f32 -> out [N][K] bf16
    const float* in;
    u16* out;
    int n0, k0, N;
    if (bid < 4096 + 3072) {
        int loc = bid - 4096;
        in = wa; out = wat; N = 3072;
        n0 = (loc % 96) * 32; k0 = (loc / 96) * 32;
    } else {
        int loc = bid - 4096 - 3072;
        in = wp; out = wpt; N = 1024;
        n0 = (loc & 31) * 32; k0 = (loc >> 5) * 32;
    }
    __shared__ float tile[32][33];
    const int tx = tid & 31, ty = tid >> 5;  // (32,8)
#pragma unroll
    for (int j = 0; j < 32; j += 8)
        tile[ty + j][tx] = in[(size_t)(k0 + ty + j) * N + n0 + tx];
    __syncthreads();
#pragma unroll
    for (int j = 0; j < 32; j += 8)
        out[(size_t)(n0 + ty + j) * 1024 + k0 + tx] = f2bf(tile[tx][ty + j]);
}

// ------ GEMM1 (m97 pattern, 128x128): kqv = x_bf @ wat^T, fused epi ------
__global__ __launch_bounds__(256, 2) void k_gemm1(
        const u16* __restrict__ A, const u16* __restrict__ Bt,
        u16* __restrict__ Cout, u16* __restrict__ Vt, int N, int K) {
    __shared__ u16 As[128 * 32];
    __shared__ u16 Bs[128 * 32];
    const int nbn = N >> 7;
    const int cpx = (int)gridDim.x >> 3;
    const int bid = (int)blockIdx.x;
    const int swb = (bid & 7) * cpx + (bid >> 3);
    const int bm = swb / nbn, bn = swb % nbn;
    const int tid = threadIdx.x;
    const int wv = tid >> 6, ln = tid & 63;
    const int lg = ln >> 4, lr = ln & 15;
    const int wr = (wv >> 1) << 6, wc = (wv & 1) << 6;

    const u16* gA = A + (size_t)(bm * 128 + wv * 32 + (ln >> 2)) * K + (ln & 3) * 8;
    const u16* gB = Bt + (size_t)(bn * 128 + wv * 32 + (ln >> 2)) * K + (ln & 3) * 8;
    u16* lA = As + wv * 1024;
    u16* lB = Bs + wv * 1024;

    f32x4 acc[4][4] = {};

    for (int k0 = 0; k0 < K; k0 += 32) {
        gload16(gA + k0, lA);
        gload16(gA + k0 + 16 * K, lA + 512);
        gload16(gB + k0, lB);
        gload16(gB + k0 + 16 * K, lB + 512);
        __syncthreads();
        s16x8 af[4], bf[4];
#pragma unroll
        for (int mi = 0; mi < 4; ++mi)
            af[mi] = *(const s16x8*)&As[(wr + mi * 16 + lr) * 32 + lg * 8];
#pragma unroll
        for (int ni = 0; ni < 4; ++ni)
            bf[ni] = *(const s16x8*)&Bs[(wc + ni * 16 + lr) * 32 + lg * 8];
#pragma unroll
        for (int mi = 0; mi < 4; ++mi)
#pragma unroll
            for (int ni = 0; ni < 4; ++ni)
                acc[mi][ni] = __builtin_amdgcn_mfma_f32_16x16x32_bf16(
                        af[mi], bf[ni], acc[mi][ni], 0, 0, 0);
        __syncthreads();
    }

    const int crow0 = bm * 128 + wr + lg * 4;
    const int ccol0 = bn * 128 + wc + lr;
    if (bn < 16) {  // K and Q thirds; Q pre-scaled by 0.125*log2(e)
        const float qs = (bn >= 8) ? 0.18033688011112042f : 1.0f;
#pragma unroll
        for (int mi = 0; mi < 4; ++mi)
#pragma unroll
            for (int ni = 0; ni < 4; ++ni)
#pragma unroll
                for (int r = 0; r < 4; ++r)
                    Cout[(size_t)(crow0 + mi * 16 + r) * 3072 + ccol0 + ni * 16] =
                            f2bf(acc[mi][ni][r] * qs);
    } else {  // V third -> Vt[(b*1024 + hd)][t]
#pragma unroll
        for (int mi = 0; mi < 4; ++mi) {
            int row = crow0 + mi * 16;
            int bb = row >> 11, t = row & 2047;
#pragma unroll
            for (int ni = 0; ni < 4; ++ni) {
                int hd = ccol0 + ni * 16 - 2048;
                uint2 pk;
                pk.x = pk_bf16(acc[mi][ni][0], acc[mi][ni][1]);
                pk.y = pk_bf16(acc[mi][ni][2], acc[mi][ni][3]);
                *(uint2*)&Vt[(size_t)(bb * 1024 + hd) * 2048 + t] = pk;
            }
        }
    }
}

// ------ GEMM2 (64x128 tiles, fp32 out): out = yb @ wpt^T ------
// 512 blocks -> 2+ blocks/CU (vs 256 blocks = 1/CU at 128x128).
__global__ __launch_bounds__(256, 4) void k_gemm2(
        const u16* __restrict__ A, const u16* __restrict__ Bt,
        float* __restrict__ Co, int N, int K) {
    __shared__ u16 As[64 * 32];
    __shared__ u16 Bs[128 * 32];
    const int nbn = N >> 7;            // 8
    const int cpx = (int)gridDim.x >> 3;
    const int bid = (int)blockIdx.x;
    const int swb = (bid & 7) * cpx + (bid >> 3);
    const int bm = swb / nbn, bn = swb % nbn;
    const int tid = threadIdx.x;
    const int wv = tid >> 6, ln = tid & 63;
    const int lg = ln >> 4, lr = ln & 15;

    const u16* gA = A + (size_t)(bm * 64 + wv * 16 + (ln >> 2)) * K + (ln & 3) * 8;
    const u16* gB = Bt + (size_t)(bn * 128 + wv * 32 + (ln >> 2)) * K + (ln & 3) * 8;
    u16* lA = As + wv * 512;
    u16* lB = Bs + wv * 1024;

    f32x4 acc[4][2] = {};

    for (int k0 = 0; k0 < K; k0 += 32) {
        gload16(gA + k0, lA);
        gload16(gB + k0, lB);
        gload16(gB + k0 + 16 * K, lB + 512);
        __syncthreads();
        s16x8 af[4], bf[2];
#pragma unroll
        for (int mi = 0; mi < 4; ++mi)
            af[mi] = *(const s16x8*)&As[(mi * 16 + lr) * 32 + lg * 8];
#pragma unroll
        for (int ni = 0; ni < 2; ++ni)
            bf[ni] = *(const s16x8*)&Bs[(wv * 32 + ni * 16 + lr) * 32 + lg * 8];
#pragma unroll
        for (int mi = 0; mi < 4; ++mi)
#pragma unroll
            for (int ni = 0; ni < 2; ++ni)
                acc[mi][ni] = __builtin_amdgcn_mfma_f32_16x16x32_bf16(
                        af[mi], bf[ni], acc[mi][ni], 0, 0, 0);
        __syncthreads();
    }

    const int crow0 = bm * 64 + lg * 4;
    const int ccol0 = bn * 128 + wv * 32 + lr;
#pragma unroll
    for (int mi = 0; mi < 4; ++mi)
#pragma unroll
        for (int ni = 0; ni < 2; ++ni)
#pragma unroll
            for (int r = 0; r < 4; ++r)
                Co[(size_t)(crow0 + mi * 16 + r) * N + ccol0 + ni * 16] =
                        acc[mi][ni][r];
}

// -------- causal flash attention: swapped QK^T, 4-5 blocks/CU --------
// 1024 blocks x 256 threads (4 waves), one 64-row q-tile per block,
// KVBLK=64, double-buffered gload_lds staging (32 KB LDS total).
// Same-CU blocks {c,c+256,c+512,c+768} get qt spread by 8/16/24 (and
// different bh), so per-CU work is 48..76 tiles (mean 66) -- R5's
// identical-qt trap avoided; qt descends in dispatch order (LPT).
// P redistribution in regs via permlane32+16 swap; no-max exp2 softmax;
// l via ones-MFMA; Q pre-scaled to log2 units by gemm1.
__global__ __launch_bounds__(256, 4) void k_attn(
        const u16* __restrict__ kqv, const u16* __restrict__ Vt,
        u16* __restrict__ y) {
    const int orig = blockIdx.x;
    const int xcd = orig & 7, slot = orig >> 3;   // HW: block i -> XCD i%8
    const int bh_l = slot >> 5, q_i = slot & 31;
    const int bh = xcd * 4 + bh_l;
    const int qt = 31 - ((q_i + 8 * bh_l) & 31);
    const int b = bh >> 4, h = bh & 15;
    const int tid = threadIdx.x;
    const int wave = tid >> 6, lane = tid & 63;
    const int lg = lane >> 4, lr = lane & 15;

    __shared__ u16 Ks[2][64 * 64];   // [buf][krow*64+d], 8B-chunk XOR-swizzled
    __shared__ u16 Vs[2][64 * 64];   // [buf][d*64+t],    same swizzle

    const u16* Kg = kqv + (size_t)b * 2048 * 3072 + h * 64;
    const u16* Qg = Kg + 1024;
    const u16* Vg = Vt + (size_t)bh * 64 * 2048;

    // staging: wave stages 16 rows (2 issues of 8); lane -> row_local
    // lane>>3, 16B-granule lane&7; global chunk = granule ^ (row&7).
    const int cK = (lane & 7) ^ (lane >> 3);
    const u16* kg0 = Kg + (size_t)(wave * 16 + (lane >> 3)) * 3072 + cK * 8;
    const u16* vg0 = Vg + (size_t)(wave * 16 + (lane >> 3)) * 2048 + cK * 8;
    const int swz = lr & 7;          // read-side chunk XOR (row&7 == lr&7)

    const int nkt = qt + 1;
    const int qbase = qt * 64 + wave * 16;

    // Q fragments (B-operand: q = lr, d = lg*8..+7), pre-scaled
    const u16* qrp = Qg + (size_t)(qbase + lr) * 3072;
    const s16x8 qf0 = *(const s16x8*)(qrp + lg * 8);
    const s16x8 qf1 = *(const s16x8*)(qrp + 32 + lg * 8);

    s16x8 ones;
#pragma unroll
    for (int i = 0; i < 8; ++i) ones[i] = (short)0x3F80;  // bf16 1.0

    f32x4 o[4] = {};  // O^T frags: d = dt*16+lg*4+r, q = lr
    f32x4 l4 = {};    // row-sum (every elem equals the row sum)

#define STAGE(bb, t)                                          \
    {                                                         \
        const u16* kp_ = kg0 + (size_t)(t) * 64 * 3072;       \
        const u16* vp_ = vg0 + (size_t)(t) * 64;              \
        gload16(kp_, &Ks[bb][wave * 1024]);                   \
        gload16(kp_ + 8 * 3072, &Ks[bb][wave * 1024 + 512]);  \
        gload16(vp_, &Vs[bb][wave * 1024]);                   \
        gload16(vp_ + 8 * 2048, &Vs[bb][wave * 1024 + 512]);  \
    }

    STAGE(0, 0);
    asm volatile("s_waitcnt vmcnt(0)\n\ts_barrier" ::: "memory");

    for (int t = 0; t < nkt; ++t) {
        const int cur = t & 1;
        if (t + 1 < nkt) STAGE(cur ^ 1, t + 1);  // flies under compute

        // S^T[k][q] = mfma(K,Q); lane: k = kb*16+lg*4+r, q = lr
        f32x4 st[4];
        __builtin_amdgcn_s_setprio(1);
#pragma unroll
        for (int kb = 0; kb < 4; ++kb) {
            const int row = kb * 16 + lr;
            s16x8 kf0 = *(const s16x8*)&Ks[cur][row * 64 + ((lg ^ swz) << 3)];
            s16x8 kf1 = *(const s16x8*)&Ks[cur][row * 64 + (((4 + lg) ^ swz) << 3)];
            f32x4 z = {};
            z = __builtin_amdgcn_mfma_f32_16x16x32_bf16(kf0, qf0, z, 0, 0, 0);
            z = __builtin_amdgcn_mfma_f32_16x16x32_bf16(kf1, qf1, z, 0, 0, 0);
            st[kb] = z;
        }
        __builtin_amdgcn_s_setprio(0);

        // p = exp2(st); causal mask only on the diagonal tile
        if (t == nkt - 1) {
            const int q_abs = qbase + lr;
            const int kb0 = t * 64 + lg * 4;
#pragma unroll
            for (int kb = 0; kb < 4; ++kb)
#pragma unroll
                for (int r = 0; r < 4; ++r)
                    st[kb][r] = EXP2((kb0 + kb * 16 + r <= q_abs)
                                         ? st[kb][r] : -3e38f);
        } else {
#pragma unroll
            for (int kb = 0; kb < 4; ++kb)
#pragma unroll
                for (int r = 0; r < 4; ++r) st[kb][r] = EXP2(st[kb][r]);
        }

        // pack to bf16 pairs + in-register redistribution (R7-verified)
        u32 E[2][2], O[2][2];
#pragma unroll
        for (int kbh = 0; kbh < 2; ++kbh)
#pragma unroll
            for (int hh = 0; hh < 2; ++hh) {
                E[kbh][hh] = cvtpk(st[2 * kbh][2 * hh], st[2 * kbh][2 * hh + 1]);
                O[kbh][hh] = cvtpk(st[2 * kbh + 1][2 * hh], st[2 * kbh + 1][2 * hh + 1]);
            }
#pragma unroll
        for (int kbh = 0; kbh < 2; ++kbh)
#pragma unroll
            for (int hh = 0; hh < 2; ++hh) {
                pl32swap(E[kbh][hh], O[kbh][hh]);
                pl16swap(E[kbh][hh], O[kbh][hh]);
            }

        // O^T += mfma(V^T, P);  l += mfma(ones, P)
        __builtin_amdgcn_s_setprio(1);
#pragma unroll
        for (int half = 0; half < 2; ++half) {
            u32x4 pw;
            pw.x = E[half][0];
            pw.y = E[half][1];
            pw.z = O[half][0];
            pw.w = O[half][1];
            s16x8 pf = __builtin_bit_cast(s16x8, pw);
            l4 = __builtin_amdgcn_mfma_f32_16x16x32_bf16(ones, pf, l4, 0, 0, 0);
#pragma unroll
            for (int dt = 0; dt < 4; ++dt) {
                const int vrow = dt * 16 + lr;
                s16x8 vf = *(const s16x8*)&Vs[cur][vrow * 64 +
                                                   (((half * 4 + lg) ^ swz) << 3)];
                o[dt] = __builtin_amdgcn_mfma_f32_16x16x32_bf16(vf, pf, o[dt], 0, 0, 0);
            }
        }
        __builtin_amdgcn_s_setprio(0);

        // next tile staged & all waves done reading cur
        asm volatile("s_waitcnt vmcnt(0)\n\ts_barrier" ::: "memory");
    }
#undef STAGE

    // normalize + write y[b*2048+q][h*64+d]; lane: q=qbase+lr, d=dt*16+lg*4+r
    const float inv = 1.0f / l4[0];
    u16* yb = y + (size_t)(b * 2048 + qbase + lr) * 1024 + h * 64;
#pragma unroll
    for (int dt = 0; dt < 4; ++dt) {
        uint2 w;
        w.x = cvtpk(o[dt][0] * inv, o[dt][1] * inv);
        w.y = cvtpk(o[dt][2] * inv, o[dt][3] * inv);
        *(uint2*)(yb + dt * 16 + lg * 4) = w;
    }
}

extern "C" void kernel_launch(void* const* d_in, const int* in_sizes, int n_in,
                              void* d_out, int out_size, void* d_ws, size_t ws_size,
                              hipStream_t stream) {
    const float* x = (const float*)d_in[0];
    const float* w_attn = (const float*)d_in[1];
    const float* w_proj = (const float*)d_in[2];
    float* out = (float*)d_out;
    char* ws = (char*)d_ws;

    u16* x_bf = (u16*)(ws);                        // 8 MB   [4096,1024]
    u16* wat  = (u16*)(ws + (size_t)(8 << 20));    // 6 MB   [3072,1024] = w_attn^T
    u16* wpt  = (u16*)(ws + (size_t)(14 << 20));   // 2 MB   [1024,1024] = w_proj^T
    u16* kqv  = (u16*)(ws + (size_t)(16 << 20));   // 24 MB  [4096,3072] (K,Q thirds)
    u16* vt   = (u16*)(ws + (size_t)(40 << 20));   // 8 MB   [B*H*D, T]
    u16* yb   = (u16*)(ws + (size_t)(48 << 20));   // 8 MB   [4096,1024]

    k_prep<<<4096 + 3072 + 1024, 256, 0, stream>>>(x, x_bf, w_attn, wat,
                                                   w_proj, wpt);
    k_gemm1<<<32 * 24, 256, 0, stream>>>(x_bf, wat, kqv, vt, 3072, 1024);
    k_attn<<<1024, 256, 0, stream>>>(kqv, vt, yb);
    k_gemm2<<<64 * 8, 256, 0, stream>>>(yb, wpt, out, 1024, 1024);
}